// Round 1
// baseline (207.064 us; speedup 1.0000x reference)
//
#include <hip/hip_runtime.h>

// QDense: out = s * (U X U^H)[:128,:128] / tr + (1-s) * diag(softmax(rand_w))
// B=512, D=256, O=128.  One workgroup (512 thr = 8 waves) per batch.
// Stage A: Y = X * U_sub^H   (contract over X's fast axis; A=X rows, B=U rows)
// Stage B: sub = U_sub * Y   (A=U rows, B=Y^T rows from swizzled LDS)

typedef __attribute__((ext_vector_type(4))) float f32x4;
typedef __attribute__((ext_vector_type(8))) short bf16x8;
typedef __attribute__((ext_vector_type(4))) short bf16x4;

static __device__ __forceinline__ short f2bf(float f) {
    unsigned u = __float_as_uint(f);
    u += 0x7fffu + ((u >> 16) & 1u);      // RNE
    return (short)(u >> 16);
}

static __device__ __forceinline__ f32x4 mfma16(bf16x8 a, bf16x8 b, f32x4 c) {
    return __builtin_amdgcn_mfma_f32_16x16x32_bf16(a, b, c, 0, 0, 0);
}

static __device__ __forceinline__ bf16x8 pack8(f32x4 a, f32x4 b) {
    bf16x8 r;
    r[0] = f2bf(a[0]); r[1] = f2bf(a[1]); r[2] = f2bf(a[2]); r[3] = f2bf(a[3]);
    r[4] = f2bf(b[0]); r[5] = f2bf(b[1]); r[6] = f2bf(b[2]); r[7] = f2bf(b[3]);
    return r;
}

// ---- prep: convert U rows [0,128) to bf16 (weight is (D,D,2) interleaved) ----
__global__ void qprep_u(const float* __restrict__ wt,
                        short* __restrict__ Ur, short* __restrict__ Ui) {
    int idx = blockIdx.x * 256 + threadIdx.x;         // 0..32767 = j*256+k, j<128
    float2 v = ((const float2*)wt)[idx];
    Ur[idx] = f2bf(v.x);
    Ui[idx] = f2bf(v.y);
}

// ---- prep: p = softmax(rand_w) (128), s = sigmoid(lam) ----
__global__ void qprep_ps(const float* __restrict__ rw, const float* __restrict__ lm,
                         float* __restrict__ pv, float* __restrict__ sv) {
    int t = threadIdx.x;                               // 64 threads
    float w0 = rw[t], w1 = rw[t + 64];
    float m = fmaxf(w0, w1);
    #pragma unroll
    for (int o = 32; o > 0; o >>= 1) m = fmaxf(m, __shfl_xor(m, o));
    float e0 = expf(w0 - m), e1 = expf(w1 - m);
    float ss = e0 + e1;
    #pragma unroll
    for (int o = 32; o > 0; o >>= 1) ss += __shfl_xor(ss, o);
    pv[t] = e0 / ss;
    pv[t + 64] = e1 / ss;
    if (t == 0) sv[0] = 1.f / (1.f + expf(-lm[0]));
}

// ---- main fused kernel: one block per batch ----
__global__ __launch_bounds__(512, 2) void qmain(
    const float* __restrict__ xr, const float* __restrict__ xi,
    const short* __restrict__ Ur, const short* __restrict__ Ui,
    const float* __restrict__ pv, const float* __restrict__ sv,
    float* __restrict__ out)
{
    // LDS: Y^T staged as bf16.  Ylr: bytes [0,32768), Yli: [32768,65536).
    // Row (= j2, 128 rows) stride 256 B (128 j-values * 2 B), XOR-swizzled.
    __shared__ __align__(16) char smem[65536];

    const int b    = blockIdx.x;
    const int tid  = threadIdx.x;
    const int lane = tid & 63;
    const int w    = tid >> 6;           // wave 0..7
    const int c16  = lane & 15;
    const int g4   = lane >> 4;          // 0..3
    const int wm   = w >> 2;             // 0..1 (stage B row-half)
    const int wn   = w & 3;              // 0..3 (stage B col-quarter)

    const float* xrb = xr + ((size_t)b << 16);
    const float* xib = xi + ((size_t)b << 16);

    f32x4 zero = {0.f, 0.f, 0.f, 0.f};
    f32x4 sR[4][2], sI[4][2];
    #pragma unroll
    for (int m = 0; m < 4; ++m)
        #pragma unroll
        for (int n = 0; n < 2; ++n) { sR[m][n] = zero; sI[m][n] = zero; }

    for (int jt = 0; jt < 256; jt += 128) {
        // ---------- stage A: Y[jt..jt+127][0..127] = (X U^H) rows ----------
        // wave w owns X rows jt + w*16 .. +16  (each X element loaded once)
        f32x4 yR[8], yI[8];
        #pragma unroll
        for (int n = 0; n < 8; ++n) { yR[n] = zero; yI[n] = zero; }

        const float* xr_row = xrb + (size_t)(jt + w * 16 + c16) * 256 + g4 * 8;
        const float* xi_row = xib + (size_t)(jt + w * 16 + c16) * 256 + g4 * 8;

        #pragma unroll 2
        for (int ks = 0; ks < 8; ++ks) {
            f32x4 a0 = *(const f32x4*)(xr_row + ks * 32);
            f32x4 a1 = *(const f32x4*)(xr_row + ks * 32 + 4);
            f32x4 b0 = *(const f32x4*)(xi_row + ks * 32);
            f32x4 b1 = *(const f32x4*)(xi_row + ks * 32 + 4);
            bf16x8 axr = pack8(a0, a1);
            bf16x8 axi = pack8(b0, b1);
            bf16x8 axrn = axr ^ (short)0x8000;

            const short* urk = Ur + ks * 32 + g4 * 8;
            const short* uik = Ui + ks * 32 + g4 * 8;
            #pragma unroll
            for (int nt = 0; nt < 8; ++nt) {
                int j2 = nt * 16 + c16;
                bf16x8 bur = *(const bf16x8*)(urk + j2 * 256);
                bf16x8 bui = *(const bf16x8*)(uik + j2 * 256);
                // Yr = Xr Ur^T + Xi Ui^T ; Yi = Xi Ur^T - Xr Ui^T
                yR[nt] = mfma16(axr, bur, yR[nt]);
                yR[nt] = mfma16(axi, bui, yR[nt]);
                yI[nt] = mfma16(axi, bur, yI[nt]);
                yI[nt] = mfma16(axrn, bui, yI[nt]);
            }
        }

        __syncthreads();   // prior stage-B LDS reads complete before overwrite

        // write Y^T to LDS: Ylds[j2][j_local], 4 consecutive j per lane (8B)
        {
            int wj = (w * 16 + g4 * 4) * 2;     // byte offset within row
            #pragma unroll
            for (int nt = 0; nt < 8; ++nt) {
                int j2 = nt * 16 + c16;
                int off = j2 * 256 + (wj ^ ((j2 & 7) << 4));
                bf16x4 pr, pi;
                pr[0] = f2bf(yR[nt][0]); pr[1] = f2bf(yR[nt][1]);
                pr[2] = f2bf(yR[nt][2]); pr[3] = f2bf(yR[nt][3]);
                pi[0] = f2bf(yI[nt][0]); pi[1] = f2bf(yI[nt][1]);
                pi[2] = f2bf(yI[nt][2]); pi[3] = f2bf(yI[nt][3]);
                *(bf16x4*)(smem + off)         = pr;
                *(bf16x4*)(smem + 32768 + off) = pi;
            }
        }
        __syncthreads();

        // ---------- stage B: sub += U_sub[:, jt..jt+127] * Y ----------
        #pragma unroll
        for (int ks2 = 0; ks2 < 4; ++ks2) {
            bf16x8 aur[4], aui[4], auin[4];
            #pragma unroll
            for (int mt = 0; mt < 4; ++mt) {
                int i = wm * 64 + mt * 16 + c16;
                const short* pa = Ur + (size_t)i * 256 + jt + ks2 * 32 + g4 * 8;
                const short* pb = Ui + (size_t)i * 256 + jt + ks2 * 32 + g4 * 8;
                aur[mt]  = *(const bf16x8*)pa;
                aui[mt]  = *(const bf16x8*)pb;
                auin[mt] = aui[mt] ^ (short)0x8000;
            }
            #pragma unroll
            for (int nt = 0; nt < 2; ++nt) {
                int j2 = wn * 32 + nt * 16 + c16;
                int off = j2 * 256 + ((ks2 * 64 + g4 * 16) ^ ((j2 & 7) << 4));
                bf16x8 byr = *(const bf16x8*)(smem + off);
                bf16x8 byi = *(const bf16x8*)(smem + 32768 + off);
                #pragma unroll
                for (int mt = 0; mt < 4; ++mt) {
                    // sub_r = Ur Yr - Ui Yi ; sub_i = Ui Yr + Ur Yi
                    sR[mt][nt] = mfma16(aur[mt],  byr, sR[mt][nt]);
                    sR[mt][nt] = mfma16(auin[mt], byi, sR[mt][nt]);
                    sI[mt][nt] = mfma16(aui[mt],  byr, sI[mt][nt]);
                    sI[mt][nt] = mfma16(aur[mt],  byi, sI[mt][nt]);
                }
            }
        }
    }

    // ---------- epilogue: trace, normalize, blend, store ----------
    __syncthreads();                       // Y LDS dead; reuse for reduction
    float loc = 0.f;
    #pragma unroll
    for (int mt = 0; mt < 4; ++mt)
        #pragma unroll
        for (int nt = 0; nt < 2; ++nt) {
            int colc = wn * 32 + nt * 16 + c16;
            #pragma unroll
            for (int r = 0; r < 4; ++r) {
                int row = wm * 64 + mt * 16 + g4 * 4 + r;
                if (row == colc) loc += sR[mt][nt][r];
            }
        }
    #pragma unroll
    for (int o = 32; o > 0; o >>= 1) loc += __shfl_xor(loc, o);
    float* red = (float*)smem;
    if (lane == 0) red[w] = loc;
    __syncthreads();
    float tr = red[0] + red[1] + red[2] + red[3] + red[4] + red[5] + red[6] + red[7];

    float s     = sv[0];
    float inv   = s / tr;
    float onems = 1.f - s;
    float* outr = out + (size_t)b * 16384;
    float* outi = out + 8388608 + (size_t)b * 16384;

    #pragma unroll
    for (int mt = 0; mt < 4; ++mt)
        #pragma unroll
        for (int nt = 0; nt < 2; ++nt) {
            int colc = wn * 32 + nt * 16 + c16;
            #pragma unroll
            for (int r = 0; r < 4; ++r) {
                int row = wm * 64 + mt * 16 + g4 * 4 + r;
                float vr = sR[mt][nt][r] * inv;
                if (row == colc) vr += onems * pv[row];
                outr[row * 128 + colc] = vr;
                outi[row * 128 + colc] = sI[mt][nt][r] * inv;
            }
        }
}

extern "C" void kernel_launch(void* const* d_in, const int* in_sizes, int n_in,
                              void* d_out, int out_size, void* d_ws, size_t ws_size,
                              hipStream_t stream) {
    (void)in_sizes; (void)n_in; (void)out_size; (void)ws_size;
    const float* xr = (const float*)d_in[0];
    const float* xi = (const float*)d_in[1];
    const float* wt = (const float*)d_in[2];
    const float* rw = (const float*)d_in[3];
    const float* lm = (const float*)d_in[4];

    short* Ur = (short*)d_ws;                       // 128*256 bf16
    short* Ui = Ur + 32768;                         // 128*256 bf16
    float* pv = (float*)((char*)d_ws + 131072);     // 128 f32
    float* sv = pv + 128;                           // 1 f32
    float* o  = (float*)d_out;

    qprep_u<<<dim3(128), dim3(256), 0, stream>>>(wt, Ur, Ui);
    qprep_ps<<<dim3(1), dim3(64), 0, stream>>>(rw, lm, pv, sv);
    qmain<<<dim3(512), dim3(512), 0, stream>>>(xr, xi, Ur, Ui, pv, sv, o);
}